// Round 9
// baseline (121.014 us; speedup 1.0000x reference)
//
#include <hip/hip_runtime.h>
#include <stdint.h>

// Problem constants
#define B_TOT   65536
#define IN_DIM  512
#define H0      256
#define H1      128
#define HH      64
#define NDIS    12

#define BM      64
#define NBLK    (B_TOT / BM)   // 1024 blocks

typedef __bf16 bf16_t;
typedef __bf16 bf16x4 __attribute__((ext_vector_type(4)));
typedef __bf16 bf16x8 __attribute__((ext_vector_type(8)));
typedef float  f32x4  __attribute__((ext_vector_type(4)));

// ---- workspace layout (bytes) ----
#define WS_W0T   0u          // bf16 [256][512]  (W0t[c][k] = W0[k][c])
#define WS_W1T   262144u     // bf16 [128][256]
#define WS_WZT   327680u     // bf16 [12][64][128] (Wzt[d][h][e] = Wz[d][e][h])
#define WS_WIT   524288u     // bf16 [16][128]  (w_init rows, zero-padded to 16)
#define WS_AL0   528384u     // f32 [256]
#define WS_BE0   529408u     // f32 [256]
#define WS_AL1   530432u     // f32 [128]
#define WS_BE1   530944u     // f32 [128]
#define WS_Z     531456u     // bf16 [65536][128] = 16777216 B
#define WS_NEED  (531456u + 16777216u)

__device__ __forceinline__ f32x4 MF(bf16x8 a, bf16x8 b, f32x4 c) {
    return __builtin_amdgcn_mfma_f32_16x16x32_bf16(a, b, c, 0, 0, 0);
}
__device__ __forceinline__ void dma16(const void* g, void* l) {
    __builtin_amdgcn_global_load_lds(
        (const __attribute__((address_space(1))) unsigned*)g,
        (__attribute__((address_space(3))) unsigned*)l, 16, 0, 0);
}
// LDS-visibility-only barrier: no vmcnt drain.
__device__ __forceinline__ void BAR() {
    asm volatile("s_waitcnt lgkmcnt(0)\ns_barrier" ::: "memory");
}

#define PACK8(o, lo, hi) { o[0]=(bf16_t)lo[0]; o[1]=(bf16_t)lo[1]; o[2]=(bf16_t)lo[2]; o[3]=(bf16_t)lo[3]; \
                           o[4]=(bf16_t)hi[0]; o[5]=(bf16_t)hi[1]; o[6]=(bf16_t)hi[2]; o[7]=(bf16_t)hi[3]; }

// =====================================================================
// Prep: transpose + f32->bf16 weights, fold BN (+bias) into alpha/beta
// =====================================================================
__global__ void prep_kernel(const float* __restrict__ W0, const float* __restrict__ b0,
                            const float* __restrict__ g0, const float* __restrict__ bb0,
                            const float* __restrict__ mm0, const float* __restrict__ vv0,
                            const float* __restrict__ W1, const float* __restrict__ b1,
                            const float* __restrict__ g1, const float* __restrict__ bb1,
                            const float* __restrict__ mm1, const float* __restrict__ vv1,
                            const float* __restrict__ w_init, const float* __restrict__ Wz,
                            char* __restrict__ ws)
{
    bf16_t* W0t = (bf16_t*)(ws + WS_W0T);
    bf16_t* W1t = (bf16_t*)(ws + WS_W1T);
    bf16_t* Wzt = (bf16_t*)(ws + WS_WZT);
    bf16_t* wiT = (bf16_t*)(ws + WS_WIT);
    float* al0 = (float*)(ws + WS_AL0);
    float* be0 = (float*)(ws + WS_BE0);
    float* al1 = (float*)(ws + WS_AL1);
    float* be1 = (float*)(ws + WS_BE1);

    int t = blockIdx.x * 256 + threadIdx.x;   // 512*256 = 131072 threads

    { // W0t: 256*512
        int c = t >> 9, k = t & 511;
        W0t[t] = (bf16_t)W0[k * H0 + c];
    }
    if (t < H1 * H0) { // W1t
        int c = t >> 8, k = t & 255;
        W1t[t] = (bf16_t)W1[k * H1 + c];
    }
    if (t < NDIS * HH * H1) { // Wzt ; Wz is [12][128][64]
        int d = t >> 13, r = t & 8191, h = r >> 7, e = r & 127;
        Wzt[t] = (bf16_t)Wz[d * 8192 + e * 64 + h];
    }
    if (t < 16 * H1) { // w_initT (pad 12->16)
        int d = t >> 7, e = t & 127;
        wiT[t] = (d < NDIS) ? (bf16_t)w_init[d * H1 + e] : (bf16_t)0.0f;
    }
    if (t < H0) {
        float a = g0[t] * rsqrtf(vv0[t] + 1e-5f);
        al0[t] = a;
        be0[t] = (b0[t] - mm0[t]) * a + bb0[t];
    }
    if (t < H1) {
        float a = g1[t] * rsqrtf(vv1[t] + 1e-5f);
        al1[t] = a;
        be1[t] = (b1[t] - mm1[t]) * a + bb1[t];
    }
}

// =====================================================================
// ENC kernel: x -> z (bf16, to ws). 64 rows/block, 256 thr, 4 blocks/CU.
// GEMM0: x reg->bf16 LDS dbuf; W0 A-frags full-step reg lead, pinned by
// sched_barrier so the compiler cannot sink the loads to their use.
// =====================================================================
__global__ __launch_bounds__(256, 4) void enc_kernel(
    const float* __restrict__ x,
    const bf16_t* __restrict__ W0t, const bf16_t* __restrict__ W1t,
    const float* __restrict__ al0, const float* __restrict__ be0,
    const float* __restrict__ al1, const float* __restrict__ be1,
    bf16_t* __restrict__ zg)
{
    __shared__ __align__(16) char smem[33792];

    const int tid  = threadIdx.x;
    const int lane = tid & 63, w = tid >> 6;
    const int l15 = lane & 15, lg = lane >> 4;
    const int m0 = blockIdx.x * BM;

    bf16_t* xs = (bf16_t*)smem;     // dbuf 2 x [64][64] bf16 = 16384 B

    // staging map: thread -> 2 chunks (8 f32 each), rows 0..31 / 32..63
    const int r0 = tid >> 3, s0 = tid & 7;
    const float* sgp0 = x + (size_t)(m0 + r0) * IN_DIM + s0 * 8;
    const float* sgp1 = x + (size_t)(m0 + r0 + 32) * IN_DIM + s0 * 8;
    const int sd0 = r0 * 64 + ((s0 ^ (r0 & 7)) << 3);
    const int sd1 = (r0 + 32) * 64 + ((s0 ^ ((r0 + 32) & 7)) << 3);

    const bf16_t* wg = W0t + (size_t)(w * 64 + l15) * IN_DIM + lg * 8;
    const int xb0 = ((lg ^ (l15 & 7)) << 3);          // kf=0 swizzled chunk
    const int xb1 = (((4 | lg) ^ (l15 & 7)) << 3);    // kf=1

    f32x4 acc[4][4] = {};
    f32x4 lo0, hi0, lo1, hi1;
    bf16x8 aS0[4], aS1[4];          // current step's A-frags (kf0, kf1)

    // prologue: stage x(0), load x(1) regs, issue A(0)
    lo0 = *(const f32x4*)(sgp0);     hi0 = *(const f32x4*)(sgp0 + 4);
    lo1 = *(const f32x4*)(sgp1);     hi1 = *(const f32x4*)(sgp1 + 4);
    { bf16x8 o; PACK8(o, lo0, hi0); *(bf16x8*)(xs + sd0) = o; }
    { bf16x8 o; PACK8(o, lo1, hi1); *(bf16x8*)(xs + sd1) = o; }
    lo0 = *(const f32x4*)(sgp0 + 64); hi0 = *(const f32x4*)(sgp0 + 68);
    lo1 = *(const f32x4*)(sgp1 + 64); hi1 = *(const f32x4*)(sgp1 + 68);
    #pragma unroll
    for (int mf = 0; mf < 4; ++mf) {
        aS0[mf] = *(const bf16x8*)(wg + (size_t)mf * 16 * IN_DIM);
        aS1[mf] = *(const bf16x8*)(wg + (size_t)mf * 16 * IN_DIM + 32);
    }
    BAR();

    #pragma unroll 1
    for (int ks = 0; ks < 8; ++ks) {
        // stage x(ks+1) into other buffer; issue x(ks+2) loads
        if (ks < 7) {
            bf16_t* xw = xs + ((ks + 1) & 1) * 4096;
            { bf16x8 o; PACK8(o, lo0, hi0); *(bf16x8*)(xw + sd0) = o; }
            { bf16x8 o; PACK8(o, lo1, hi1); *(bf16x8*)(xw + sd1) = o; }
            if (ks < 6) {
                lo0 = *(const f32x4*)(sgp0 + (ks + 2) * 64); hi0 = *(const f32x4*)(sgp0 + (ks + 2) * 64 + 4);
                lo1 = *(const f32x4*)(sgp1 + (ks + 2) * 64); hi1 = *(const f32x4*)(sgp1 + (ks + 2) * 64 + 4);
            }
        }
        __builtin_amdgcn_sched_barrier(0);

        const bf16_t* xr = xs + (ks & 1) * 4096;
        __builtin_amdgcn_s_setprio(1);
        #pragma unroll
        for (int nf = 0; nf < 4; ++nf) {
            bf16x8 b = *(const bf16x8*)(xr + nf * 1024 + l15 * 64 + xb0);
            #pragma unroll
            for (int mf = 0; mf < 4; ++mf) acc[mf][nf] = MF(aS0[mf], b, acc[mf][nf]);
        }
        #pragma unroll
        for (int nf = 0; nf < 4; ++nf) {
            bf16x8 b = *(const bf16x8*)(xr + nf * 1024 + l15 * 64 + xb1);
            #pragma unroll
            for (int mf = 0; mf < 4; ++mf) acc[mf][nf] = MF(aS1[mf], b, acc[mf][nf]);
        }
        __builtin_amdgcn_s_setprio(0);

        // issue next step's A-frags NOW (full-step lead across the barrier)
        if (ks < 7) {
            #pragma unroll
            for (int mf = 0; mf < 4; ++mf) {
                aS0[mf] = *(const bf16x8*)(wg + (size_t)mf * 16 * IN_DIM + (ks + 1) * 64);
                aS1[mf] = *(const bf16x8*)(wg + (size_t)mf * 16 * IN_DIM + (ks + 1) * 64 + 32);
            }
        }
        __builtin_amdgcn_sched_barrier(0);
        BAR();
    }

    // ---- P1: BN0 + ReLU -> hs [64][264] bf16 (overwrites xs) ----
    {
        bf16_t* hs = (bf16_t*)smem;
        #pragma unroll
        for (int mf = 0; mf < 4; ++mf) {
            int c = w * 64 + mf * 16 + lg * 4;
            f32x4 al = *(const f32x4*)(al0 + c);
            f32x4 be = *(const f32x4*)(be0 + c);
            #pragma unroll
            for (int nf = 0; nf < 4; ++nf) {
                int r = nf * 16 + l15;
                bf16x4 o;
                #pragma unroll
                for (int j = 0; j < 4; ++j)
                    o[j] = (bf16_t)fmaxf(acc[mf][nf][j] * al[j] + be[j], 0.f);
                *(bf16x4*)(hs + r * 264 + c) = o;
            }
        }
    }
    BAR();

    // ---- P2: GEMM1 (z^T = W1t @ h-rows), A 1-kf-ahead from L2 ----
    {
        const bf16_t* hs  = (const bf16_t*)smem;
        const bf16_t* w1g = W1t + (size_t)(w * 32 + l15) * H0 + lg * 8;
        f32x4 acc2[2][4] = {};
        bf16x8 aP[2], aQ[2];
        aP[0] = *(const bf16x8*)(w1g);
        aP[1] = *(const bf16x8*)(w1g + 16 * H0);
        aQ[0] = *(const bf16x8*)(w1g + 32);
        aQ[1] = *(const bf16x8*)(w1g + 16 * H0 + 32);
        #pragma unroll
        for (int kf = 0; kf < 8; ++kf) {
            bf16x8 ac0 = (kf & 1) ? aQ[0] : aP[0];
            bf16x8 ac1 = (kf & 1) ? aQ[1] : aP[1];
            if (kf < 6) {
                if (kf & 1) {
                    aQ[0] = *(const bf16x8*)(w1g + (kf + 2) * 32);
                    aQ[1] = *(const bf16x8*)(w1g + 16 * H0 + (kf + 2) * 32);
                } else {
                    aP[0] = *(const bf16x8*)(w1g + (kf + 2) * 32);
                    aP[1] = *(const bf16x8*)(w1g + 16 * H0 + (kf + 2) * 32);
                }
            }
            #pragma unroll
            for (int nf = 0; nf < 4; ++nf) {
                bf16x8 b = *(const bf16x8*)(hs + (nf * 16 + l15) * 264 + kf * 32 + lg * 8);
                acc2[0][nf] = MF(ac0, b, acc2[0][nf]);
                acc2[1][nf] = MF(ac1, b, acc2[1][nf]);
            }
        }
        // BN1 + ReLU -> z (bf16) straight to global ws
        #pragma unroll
        for (int mf = 0; mf < 2; ++mf) {
            int c = w * 32 + mf * 16 + lg * 4;
            f32x4 al = *(const f32x4*)(al1 + c);
            f32x4 be = *(const f32x4*)(be1 + c);
            #pragma unroll
            for (int nf = 0; nf < 4; ++nf) {
                int r = nf * 16 + l15;
                bf16x4 o;
                #pragma unroll
                for (int j = 0; j < 4; ++j)
                    o[j] = (bf16_t)fmaxf(acc2[mf][nf][j] * al[j] + be[j], 0.f);
                *(bf16x4*)(zg + (size_t)(m0 + r) * H1 + c) = o;
            }
        }
    }
}

// =====================================================================
// HEAD kernel: z -> out. 64 rows/block, 256 thr, 4 blocks/CU.
// z staged via global_load_lds (raw bf16); P4 with 1-d-ahead prefetch.
// =====================================================================
#define HL_PS    16384u
#define HL_PART  21504u
#define HL_TOTAL 33792u

__global__ __launch_bounds__(256, 4) void head_kernel(
    const bf16_t* __restrict__ zg,
    const bf16_t* __restrict__ Wzt, const bf16_t* __restrict__ wiT,
    const float* __restrict__ b_init, const float* __restrict__ Wp,
    const float* __restrict__ bh, const float* __restrict__ Wo,
    const float* __restrict__ bo, const float* __restrict__ pred_w,
    const int* __restrict__ pred_idx, float* __restrict__ out)
{
    __shared__ __align__(16) char smem[HL_TOTAL];

    const int tid  = threadIdx.x;
    const int lane = tid & 63, w = tid >> 6;
    const int l15 = lane & 15, lg = lane >> 4;
    const int m0 = blockIdx.x * BM;

    // stage z tile [64][128] bf16 = 16 KB via dma (wave w -> quarter)
    {
        const char* zsrc = (const char*)zg + (size_t)blockIdx.x * 16384 + w * 4096;
        char* zdst = smem + w * 4096;
        #pragma unroll
        for (int i = 0; i < 4; ++i)
            dma16(zsrc + i * 1024 + lane * 16, zdst + i * 1024);
    }

    const bf16_t* zs = (const bf16_t*)smem;
    float* psf  = (float*)(smem + HL_PS);     // [64][20] f32
    float* part = (float*)(smem + HL_PART);   // [12][64][4] f32
    const bf16_t* wzg = Wzt + (size_t)(w * 16 + l15) * H1 + lg * 8;
    const int hb = w * 16 + lg * 4;

    // prefetch d=0 A-frags + epilogue constants while dma is in flight
    bf16x8 az0 = *(const bf16x8*)(wzg);
    bf16x8 az1 = *(const bf16x8*)(wzg + 32);
    bf16x8 az2 = *(const bf16x8*)(wzg + 64);
    bf16x8 az3 = *(const bf16x8*)(wzg + 96);
    int   ci0 = pred_idx[0], ci1 = pred_idx[1], ci2 = pred_idx[2];
    float cq0 = pred_w[0],  cq1 = pred_w[1],  cq2 = pred_w[2];
    f32x4 cbh = *(const f32x4*)(bh + hb);
    f32x4 cwo = *(const f32x4*)(Wo + hb);
    f32x4 cpa = *(const f32x4*)(Wp + hb);
    f32x4 cpb = *(const f32x4*)(Wp + 64 + hb);
    f32x4 cpc = *(const f32x4*)(Wp + 128 + hb);

    asm volatile("s_waitcnt vmcnt(0) lgkmcnt(0)\ns_barrier" ::: "memory");

    // ---- P3: p = sigmoid(z @ w_init^T) ----
    {
        f32x4 pacc = {};
        #pragma unroll
        for (int kf = 0; kf < 4; ++kf) {
            bf16x8 aw = *(const bf16x8*)(wiT + l15 * H1 + kf * 32 + lg * 8);
            bf16x8 bz = *(const bf16x8*)(zs + (w * 16 + l15) * H1 + kf * 32 + lg * 8);
            pacc = MF(aw, bz, pacc);
        }
        f32x4 pv;
        #pragma unroll
        for (int j = 0; j < 4; ++j) {
            int d = lg * 4 + j;
            float bi = (d < NDIS) ? b_init[d] : 0.f;
            pv[j] = 1.f / (1.f + __expf(-(pacc[j] + bi)));
        }
        *(f32x4*)(psf + (w * 16 + l15) * 20 + lg * 4) = pv;
    }
    BAR();

    // ---- P4: 12 heads, all operands prefetched 1 d ahead ----
    #pragma unroll 1
    for (int d = 0; d < NDIS; ++d) {
        bf16x8 an0 = az0, an1 = az1, an2 = az2, an3 = az3;
        int   ni0 = ci0, ni1 = ci1, ni2 = ci2;
        float nq0 = cq0, nq1 = cq1, nq2 = cq2;
        f32x4 nbh = cbh, nwo = cwo, npa = cpa, npb = cpb, npc = cpc;
        if (d < NDIS - 1) {
            const bf16_t* p = wzg + (size_t)(d + 1) * 8192;
            an0 = *(const bf16x8*)(p);      an1 = *(const bf16x8*)(p + 32);
            an2 = *(const bf16x8*)(p + 64); an3 = *(const bf16x8*)(p + 96);
            ni0 = pred_idx[(d + 1) * 3]; ni1 = pred_idx[(d + 1) * 3 + 1]; ni2 = pred_idx[(d + 1) * 3 + 2];
            nq0 = pred_w[(d + 1) * 3];   nq1 = pred_w[(d + 1) * 3 + 1];   nq2 = pred_w[(d + 1) * 3 + 2];
            nbh = *(const f32x4*)(bh + (d + 1) * 64 + hb);
            nwo = *(const f32x4*)(Wo + (d + 1) * 64 + hb);
            npa = *(const f32x4*)(Wp + (d + 1) * 192 + hb);
            npb = *(const f32x4*)(Wp + (d + 1) * 192 + 64 + hb);
            npc = *(const f32x4*)(Wp + (d + 1) * 192 + 128 + hb);
        }
        __builtin_amdgcn_sched_barrier(0);

        #pragma unroll
        for (int nf = 0; nf < 4; ++nf) {
            const bf16_t* zr = zs + (nf * 16 + l15) * H1 + lg * 8;
            f32x4 hacc = {};
            hacc = MF(az0, *(const bf16x8*)(zr),      hacc);
            hacc = MF(az1, *(const bf16x8*)(zr + 32), hacc);
            hacc = MF(az2, *(const bf16x8*)(zr + 64), hacc);
            hacc = MF(az3, *(const bf16x8*)(zr + 96), hacc);
            int r = nf * 16 + l15;
            float a0 = psf[r * 20 + ci0] * cq0;
            float a1 = psf[r * 20 + ci1] * cq1;
            float a2 = psf[r * 20 + ci2] * cq2;
            float s = 0.f;
            #pragma unroll
            for (int j = 0; j < 4; ++j) {
                float v = hacc[j] + cbh[j] + a0 * cpa[j] + a1 * cpb[j] + a2 * cpc[j];
                s += fmaxf(v, 0.f) * cwo[j];
            }
            s += __shfl_xor(s, 16);
            s += __shfl_xor(s, 32);
            if (lane < 16) part[d * 256 + r * 4 + w] = s;
        }
        az0 = an0; az1 = an1; az2 = an2; az3 = an3;
        ci0 = ni0; ci1 = ni1; ci2 = ni2;
        cq0 = nq0; cq1 = nq1; cq2 = nq2;
        cbh = nbh; cwo = nwo; cpa = npa; cpb = npb; cpc = npc;
    }
    BAR();

    // ---- final: reduce partials, sigmoid, coalesced store ----
    {
        float* obuf = (float*)(smem + HL_PS);   // aliases psf (dead)
        #pragma unroll
        for (int i = 0; i < 3; ++i) {
            int e = tid * 3 + i;                // 768 outputs = [64 rows][12 d]
            int d = e % 12, r = e / 12;
            f32x4 p = *(const f32x4*)(part + d * 256 + r * 4);
            float s = p[0] + p[1] + p[2] + p[3] + bo[d];
            obuf[e] = 1.f / (1.f + __expf(-s));
        }
    }
    BAR();
    if (tid < 192) {
        f32x4 o = *(const f32x4*)((const float*)(smem + HL_PS) + tid * 4);
        *(f32x4*)(out + (size_t)blockIdx.x * 768 + tid * 4) = o;
    }
}

// =====================================================================
extern "C" void kernel_launch(void* const* d_in, const int* in_sizes, int n_in,
                              void* d_out, int out_size, void* d_ws, size_t ws_size,
                              hipStream_t stream) {
    if (ws_size < (size_t)WS_NEED) return;

    const float* x      = (const float*)d_in[0];
    const float* W0     = (const float*)d_in[1];
    const float* b0     = (const float*)d_in[2];
    const float* g0     = (const float*)d_in[3];
    const float* bb0    = (const float*)d_in[4];
    const float* mm0    = (const float*)d_in[5];
    const float* vv0    = (const float*)d_in[6];
    const float* W1     = (const float*)d_in[7];
    const float* b1     = (const float*)d_in[8];
    const float* g1     = (const float*)d_in[9];
    const float* bb1    = (const float*)d_in[10];
    const float* mm1    = (const float*)d_in[11];
    const float* vv1    = (const float*)d_in[12];
    const float* w_init = (const float*)d_in[13];
    const float* b_init = (const float*)d_in[14];
    const float* Wz     = (const float*)d_in[15];
    const float* Wp     = (const float*)d_in[16];
    const float* bh     = (const float*)d_in[17];
    const float* Wo     = (const float*)d_in[18];
    const float* bo     = (const float*)d_in[19];
    const float* pred_w = (const float*)d_in[20];
    const int*   pred_idx = (const int*)d_in[21];

    char* ws = (char*)d_ws;
    const bf16_t* W0t = (const bf16_t*)(ws + WS_W0T);
    const bf16_t* W1t = (const bf16_t*)(ws + WS_W1T);
    const bf16_t* Wzt = (const bf16_t*)(ws + WS_WZT);
    const bf16_t* wiT = (const bf16_t*)(ws + WS_WIT);
    const float* al0 = (const float*)(ws + WS_AL0);
    const float* be0 = (const float*)(ws + WS_BE0);
    const float* al1 = (const float*)(ws + WS_AL1);
    const float* be1 = (const float*)(ws + WS_BE1);
    bf16_t* zg = (bf16_t*)(ws + WS_Z);

    prep_kernel<<<dim3(512), dim3(256), 0, stream>>>(
        W0, b0, g0, bb0, mm0, vv0, W1, b1, g1, bb1, mm1, vv1, w_init, Wz, ws);

    enc_kernel<<<dim3(NBLK), dim3(256), 0, stream>>>(
        x, W0t, W1t, al0, be0, al1, be1, zg);

    head_kernel<<<dim3(NBLK), dim3(256), 0, stream>>>(
        zg, Wzt, wiT, b_init, Wp, bh, Wo, bo, pred_w, pred_idx, (float*)d_out);
}

// Round 10
// 93.439 us; speedup vs baseline: 1.2951x; 1.2951x over previous
//
#include <hip/hip_runtime.h>
#include <stdint.h>

// Problem constants
#define B_TOT   65536
#define IN_DIM  512
#define H0      256
#define H1      128
#define HH      64
#define NDIS    12

#define BM      64
#define NBLK    (B_TOT / BM)   // 1024 blocks

typedef __bf16 bf16_t;
typedef __bf16 bf16x4 __attribute__((ext_vector_type(4)));
typedef __bf16 bf16x8 __attribute__((ext_vector_type(8)));
typedef float  f32x4  __attribute__((ext_vector_type(4)));

// ---- workspace layout (bytes) ----
#define WS_W0T   0u          // bf16 [256][512]  (W0t[c][k] = W0[k][c])
#define WS_W1T   262144u     // bf16 [128][256]
#define WS_WZT   327680u     // bf16 [12][64][128] (Wzt[d][h][e] = Wz[d][e][h])
#define WS_WIT   524288u     // bf16 [16][128]  (w_init rows, zero-padded to 16)
#define WS_AL0   528384u     // f32 [256]
#define WS_BE0   529408u     // f32 [256]
#define WS_AL1   530432u     // f32 [128]
#define WS_BE1   530944u     // f32 [128]
#define WS_NEED  531456u

// ---- fused-kernel LDS (68608 B; 2 blocks/CU) ----
// xt [64][256] bf16 swizzled @0 (32768) -> hs [64][264] bf16 @0 (33792)
// zs [64][136] bf16 @33792 ; psf [64][20] f32 @51200 ; part [12][64][4] @56320
#define L_ZS     33792u
#define L_PS     51200u
#define L_PART   56320u
#define L_TOTAL  68608u

__device__ __forceinline__ f32x4 MF(bf16x8 a, bf16x8 b, f32x4 c) {
    return __builtin_amdgcn_mfma_f32_16x16x32_bf16(a, b, c, 0, 0, 0);
}
// LDS-visibility-only barrier: no vmcnt drain (global prefetches survive).
__device__ __forceinline__ void BAR() {
    asm volatile("s_waitcnt lgkmcnt(0)\ns_barrier" ::: "memory");
}
#define SB() __builtin_amdgcn_sched_barrier(0)

#define PACK8(o, lo, hi) { o[0]=(bf16_t)lo[0]; o[1]=(bf16_t)lo[1]; o[2]=(bf16_t)lo[2]; o[3]=(bf16_t)lo[3]; \
                           o[4]=(bf16_t)hi[0]; o[5]=(bf16_t)hi[1]; o[6]=(bf16_t)hi[2]; o[7]=(bf16_t)hi[3]; }

// =====================================================================
// Prep: transpose + f32->bf16 weights, fold BN (+bias) into alpha/beta
// =====================================================================
__global__ void prep_kernel(const float* __restrict__ W0, const float* __restrict__ b0,
                            const float* __restrict__ g0, const float* __restrict__ bb0,
                            const float* __restrict__ mm0, const float* __restrict__ vv0,
                            const float* __restrict__ W1, const float* __restrict__ b1,
                            const float* __restrict__ g1, const float* __restrict__ bb1,
                            const float* __restrict__ mm1, const float* __restrict__ vv1,
                            const float* __restrict__ w_init, const float* __restrict__ Wz,
                            char* __restrict__ ws)
{
    bf16_t* W0t = (bf16_t*)(ws + WS_W0T);
    bf16_t* W1t = (bf16_t*)(ws + WS_W1T);
    bf16_t* Wzt = (bf16_t*)(ws + WS_WZT);
    bf16_t* wiT = (bf16_t*)(ws + WS_WIT);
    float* al0 = (float*)(ws + WS_AL0);
    float* be0 = (float*)(ws + WS_BE0);
    float* al1 = (float*)(ws + WS_AL1);
    float* be1 = (float*)(ws + WS_BE1);

    int t = blockIdx.x * 256 + threadIdx.x;   // 512*256 = 131072 threads

    { // W0t: 256*512
        int c = t >> 9, k = t & 511;
        W0t[t] = (bf16_t)W0[k * H0 + c];
    }
    if (t < H1 * H0) { // W1t
        int c = t >> 8, k = t & 255;
        W1t[t] = (bf16_t)W1[k * H1 + c];
    }
    if (t < NDIS * HH * H1) { // Wzt ; Wz is [12][128][64]
        int d = t >> 13, r = t & 8191, h = r >> 7, e = r & 127;
        Wzt[t] = (bf16_t)Wz[d * 8192 + e * 64 + h];
    }
    if (t < 16 * H1) { // w_initT (pad 12->16)
        int d = t >> 7, e = t & 127;
        wiT[t] = (d < NDIS) ? (bf16_t)w_init[d * H1 + e] : (bf16_t)0.0f;
    }
    if (t < H0) {
        float a = g0[t] * rsqrtf(vv0[t] + 1e-5f);
        al0[t] = a;
        be0[t] = (b0[t] - mm0[t]) * a + bb0[t];
    }
    if (t < H1) {
        float a = g1[t] * rsqrtf(vv1[t] + 1e-5f);
        al1[t] = a;
        be1[t] = (b1[t] - mm1[t]) * a + bb1[t];
    }
}

// =====================================================================
// Fused kernel: 64 rows/block, 256 thr (4 waves), 2 blocks/CU.
// x staged ONCE per 256-k half; GEMM0 = two 4-step FREE-RUN segments
// (no barriers inside). 8 barriers total per block.
// =====================================================================
__global__ __launch_bounds__(256, 2) void fused_kernel(
    const float* __restrict__ x,
    const bf16_t* __restrict__ W0t, const bf16_t* __restrict__ W1t,
    const float* __restrict__ al0, const float* __restrict__ be0,
    const float* __restrict__ al1, const float* __restrict__ be1,
    const bf16_t* __restrict__ Wzt, const bf16_t* __restrict__ wiT,
    const float* __restrict__ b_init, const float* __restrict__ Wp,
    const float* __restrict__ bh, const float* __restrict__ Wo,
    const float* __restrict__ bo, const float* __restrict__ pred_w,
    const int* __restrict__ pred_idx, float* __restrict__ out)
{
    __shared__ __align__(16) char smem[L_TOTAL];

    const int tid  = threadIdx.x;
    const int lane = tid & 63, w = tid >> 6;
    const int l15 = lane & 15, lg = lane >> 4;
    const int m0 = blockIdx.x * BM;

    // ---------------- GEMM0: h^T = W0t @ x-rows, two 256-k halves ----------
    // x tile [64][256] bf16 in LDS, 16B-chunk swizzle: phys = c ^ (row&31).
    const int srow = tid >> 2, squad = tid & 3;
    const float* sgp = x + (size_t)(m0 + srow) * IN_DIM;
    bf16_t* const xw = (bf16_t*)smem;
    const bf16_t* const xr = (const bf16_t*)smem;
    const bf16_t* wg = W0t + (size_t)(w * 64 + l15) * IN_DIM + lg * 8;

    f32x4 sv[16];
    f32x4 acc[4][4] = {};
    bf16x8 aA[8], aB[8];

#define STAGE_ISSUE(hf) { _Pragma("unroll") for (int i = 0; i < 8; ++i) { \
    int c = squad + i * 4; \
    sv[2*i]   = *(const f32x4*)(sgp + (hf) * 256 + c * 8); \
    sv[2*i+1] = *(const f32x4*)(sgp + (hf) * 256 + c * 8 + 4); } }
#define STAGE_WRITE() { _Pragma("unroll") for (int i = 0; i < 8; ++i) { \
    int c = squad + i * 4; int p = c ^ (srow & 31); \
    bf16x8 o; PACK8(o, sv[2*i], sv[2*i+1]); \
    *(bf16x8*)(xw + srow * 256 + p * 8) = o; } }
#define ISSUE_A0(gk, SET) { _Pragma("unroll") for (int mf = 0; mf < 4; ++mf) { \
    SET[mf]     = *(const bf16x8*)(wg + (size_t)mf * 16 * IN_DIM + (gk)); \
    SET[mf + 4] = *(const bf16x8*)(wg + (size_t)mf * 16 * IN_DIM + (gk) + 32); } }
#define G0_STEP(st, SET) { \
    _Pragma("unroll") for (int kf = 0; kf < 2; ++kf) \
    _Pragma("unroll") for (int nf = 0; nf < 4; ++nf) { \
        int c = (st) * 8 + kf * 4 + lg; \
        int p = c ^ (((nf & 1) << 4) | l15); \
        bf16x8 b = *(const bf16x8*)(xr + (nf * 16 + l15) * 256 + p * 8); \
        _Pragma("unroll") for (int mf = 0; mf < 4; ++mf) \
            acc[mf][nf] = MF(SET[kf * 4 + mf], b, acc[mf][nf]); } }

    // prologue: issue half0 loads + A(st0), write half0
    STAGE_ISSUE(0); SB();
    ISSUE_A0(0, aA); SB();
    STAGE_WRITE();               // compiler waits only the 16 stage loads
    BAR();

    // issue half1 loads NOW: consumed after 4 full MFMA steps (~huge lead)
    STAGE_ISSUE(1); SB();

    // free-run segment: half0, steps 0..3, A-frags one step ahead
    ISSUE_A0(64,  aB); SB(); G0_STEP(0, aA); SB();
    ISSUE_A0(128, aA); SB(); G0_STEP(1, aB); SB();
    ISSUE_A0(192, aB); SB(); G0_STEP(2, aA); SB();
    ISSUE_A0(256, aA); SB(); G0_STEP(3, aB);
    BAR();                       // all half0 reads done
    STAGE_WRITE();               // half1 overwrites xt
    BAR();

    // free-run segment: half1
    ISSUE_A0(320, aB); SB(); G0_STEP(0, aA); SB();
    ISSUE_A0(384, aA); SB(); G0_STEP(1, aB); SB();
    ISSUE_A0(448, aB); SB(); G0_STEP(2, aA); SB();
    // prefetch GEMM1 W1 A-frags before the last step
    const bf16_t* w1g = W1t + (size_t)(w * 32 + l15) * H0 + lg * 8;
    bf16x8 aP[2], aQ[2];
    aP[0] = *(const bf16x8*)(w1g);
    aP[1] = *(const bf16x8*)(w1g + 16 * H0);
    aQ[0] = *(const bf16x8*)(w1g + 32);
    aQ[1] = *(const bf16x8*)(w1g + 16 * H0 + 32);
    SB();
    G0_STEP(3, aB);
    BAR();                       // xt dead

    // ---------------- P1: BN0 + ReLU -> hs [64][264] ----------------
    {
        bf16_t* hs = (bf16_t*)smem;
        #pragma unroll
        for (int mf = 0; mf < 4; ++mf) {
            int c = w * 64 + mf * 16 + lg * 4;
            f32x4 al = *(const f32x4*)(al0 + c);
            f32x4 be = *(const f32x4*)(be0 + c);
            #pragma unroll
            for (int nf = 0; nf < 4; ++nf) {
                int r = nf * 16 + l15;
                bf16x4 o;
                #pragma unroll
                for (int j = 0; j < 4; ++j)
                    o[j] = (bf16_t)fmaxf(acc[mf][nf][j] * al[j] + be[j], 0.f);
                *(bf16x4*)(hs + r * 264 + c) = o;
            }
        }
    }
    BAR();

    // ---------------- P2: GEMM1 (z^T = W1t @ h-rows), free-run ----------------
    {
        const bf16_t* hs = (const bf16_t*)smem;
        bf16_t* zs = (bf16_t*)(smem + L_ZS);
        f32x4 acc2[2][4] = {};
        #pragma unroll
        for (int kf = 0; kf < 8; ++kf) {
            bf16x8 ac0 = (kf & 1) ? aQ[0] : aP[0];
            bf16x8 ac1 = (kf & 1) ? aQ[1] : aP[1];
            if (kf < 6) {
                if (kf & 1) {
                    aQ[0] = *(const bf16x8*)(w1g + (kf + 2) * 32);
                    aQ[1] = *(const bf16x8*)(w1g + 16 * H0 + (kf + 2) * 32);
                } else {
                    aP[0] = *(const bf16x8*)(w1g + (kf + 2) * 32);
                    aP[1] = *(const bf16x8*)(w1g + 16 * H0 + (kf + 2) * 32);
                }
            }
            #pragma unroll
            for (int nf = 0; nf < 4; ++nf) {
                bf16x8 b = *(const bf16x8*)(hs + (nf * 16 + l15) * 264 + kf * 32 + lg * 8);
                acc2[0][nf] = MF(ac0, b, acc2[0][nf]);
                acc2[1][nf] = MF(ac1, b, acc2[1][nf]);
            }
        }
        // BN1 + ReLU -> zs (disjoint region; no barrier needed before write)
        #pragma unroll
        for (int mf = 0; mf < 2; ++mf) {
            int c = w * 32 + mf * 16 + lg * 4;
            f32x4 al = *(const f32x4*)(al1 + c);
            f32x4 be = *(const f32x4*)(be1 + c);
            #pragma unroll
            for (int nf = 0; nf < 4; ++nf) {
                int r = nf * 16 + l15;
                bf16x4 o;
                #pragma unroll
                for (int j = 0; j < 4; ++j)
                    o[j] = (bf16_t)fmaxf(acc2[mf][nf][j] * al[j] + be[j], 0.f);
                *(bf16x4*)(zs + r * 136 + c) = o;
            }
        }
    }

    const bf16_t* zs = (const bf16_t*)(smem + L_ZS);
    float* psf  = (float*)(smem + L_PS);     // [64][20] f32
    float* part = (float*)(smem + L_PART);   // [12][64][4] f32
    const bf16_t* wzg = Wzt + (size_t)(w * 16 + l15) * H1 + lg * 8;
    const int hb = w * 16 + lg * 4;

    // prefetch P3 wiT frags + d=0 head frags + epilogue consts BEFORE barrier
    bf16x8 wi0 = *(const bf16x8*)(wiT + l15 * H1 + lg * 8);
    bf16x8 wi1 = *(const bf16x8*)(wiT + l15 * H1 + 32 + lg * 8);
    bf16x8 wi2 = *(const bf16x8*)(wiT + l15 * H1 + 64 + lg * 8);
    bf16x8 wi3 = *(const bf16x8*)(wiT + l15 * H1 + 96 + lg * 8);
    bf16x8 az0 = *(const bf16x8*)(wzg);
    bf16x8 az1 = *(const bf16x8*)(wzg + 32);
    bf16x8 az2 = *(const bf16x8*)(wzg + 64);
    bf16x8 az3 = *(const bf16x8*)(wzg + 96);
    int   ci0 = pred_idx[0], ci1 = pred_idx[1], ci2 = pred_idx[2];
    float cq0 = pred_w[0],  cq1 = pred_w[1],  cq2 = pred_w[2];
    f32x4 cbh = *(const f32x4*)(bh + hb);
    f32x4 cwo = *(const f32x4*)(Wo + hb);
    f32x4 cpa = *(const f32x4*)(Wp + hb);
    f32x4 cpb = *(const f32x4*)(Wp + 64 + hb);
    f32x4 cpc = *(const f32x4*)(Wp + 128 + hb);
    SB();
    BAR();                       // zs visible to all waves

    // ---------------- P3: p = sigmoid(z @ w_init^T) ----------------
    {
        const bf16_t* bz = zs + (w * 16 + l15) * 136 + lg * 8;
        f32x4 pacc = {};
        pacc = MF(wi0, *(const bf16x8*)(bz),      pacc);
        pacc = MF(wi1, *(const bf16x8*)(bz + 32), pacc);
        pacc = MF(wi2, *(const bf16x8*)(bz + 64), pacc);
        pacc = MF(wi3, *(const bf16x8*)(bz + 96), pacc);
        f32x4 pv;
        #pragma unroll
        for (int j = 0; j < 4; ++j) {
            int d = lg * 4 + j;
            float bi = (d < NDIS) ? b_init[d] : 0.f;
            pv[j] = 1.f / (1.f + __expf(-(pacc[j] + bi)));
        }
        *(f32x4*)(psf + (w * 16 + l15) * 20 + lg * 4) = pv;
    }
    BAR();                       // psf ready

    // ---------------- P4: 12 heads, free-run, 1-d-ahead prefetch -----------
    #pragma unroll 1
    for (int d = 0; d < NDIS; ++d) {
        bf16x8 an0 = az0, an1 = az1, an2 = az2, an3 = az3;
        int   ni0 = ci0, ni1 = ci1, ni2 = ci2;
        float nq0 = cq0, nq1 = cq1, nq2 = cq2;
        f32x4 nbh = cbh, nwo = cwo, npa = cpa, npb = cpb, npc = cpc;
        if (d < NDIS - 1) {
            const bf16_t* p = wzg + (size_t)(d + 1) * 8192;
            an0 = *(const bf16x8*)(p);      an1 = *(const bf16x8*)(p + 32);
            an2 = *(const bf16x8*)(p + 64); an3 = *(const bf16x8*)(p + 96);
            ni0 = pred_idx[(d + 1) * 3]; ni1 = pred_idx[(d + 1) * 3 + 1]; ni2 = pred_idx[(d + 1) * 3 + 2];
            nq0 = pred_w[(d + 1) * 3];   nq1 = pred_w[(d + 1) * 3 + 1];   nq2 = pred_w[(d + 1) * 3 + 2];
            nbh = *(const f32x4*)(bh + (d + 1) * 64 + hb);
            nwo = *(const f32x4*)(Wo + (d + 1) * 64 + hb);
            npa = *(const f32x4*)(Wp + (d + 1) * 192 + hb);
            npb = *(const f32x4*)(Wp + (d + 1) * 192 + 64 + hb);
            npc = *(const f32x4*)(Wp + (d + 1) * 192 + 128 + hb);
        }
        SB();

        #pragma unroll
        for (int nf = 0; nf < 4; ++nf) {
            const bf16_t* zr = zs + (nf * 16 + l15) * 136 + lg * 8;
            f32x4 hacc = {};
            hacc = MF(az0, *(const bf16x8*)(zr),      hacc);
            hacc = MF(az1, *(const bf16x8*)(zr + 32), hacc);
            hacc = MF(az2, *(const bf16x8*)(zr + 64), hacc);
            hacc = MF(az3, *(const bf16x8*)(zr + 96), hacc);
            int r = nf * 16 + l15;
            float a0 = psf[r * 20 + ci0] * cq0;
            float a1 = psf[r * 20 + ci1] * cq1;
            float a2 = psf[r * 20 + ci2] * cq2;
            float s = 0.f;
            #pragma unroll
            for (int j = 0; j < 4; ++j) {
                float v = hacc[j] + cbh[j] + a0 * cpa[j] + a1 * cpb[j] + a2 * cpc[j];
                s += fmaxf(v, 0.f) * cwo[j];
            }
            s += __shfl_xor(s, 16);
            s += __shfl_xor(s, 32);
            if (lane < 16) part[d * 256 + r * 4 + w] = s;
        }
        az0 = an0; az1 = an1; az2 = an2; az3 = an3;
        ci0 = ni0; ci1 = ni1; ci2 = ni2;
        cq0 = nq0; cq1 = nq1; cq2 = nq2;
        cbh = nbh; cwo = nwo; cpa = npa; cpb = npb; cpc = npc;
    }
    BAR();

    // ---------------- final: reduce partials, sigmoid, coalesced store -----
    {
        float* obuf = (float*)(smem + L_PS);   // aliases psf (dead)
        #pragma unroll
        for (int i = 0; i < 3; ++i) {
            int e = tid * 3 + i;               // 768 = [64 rows][12 d]
            int d = e % 12, r = e / 12;
            f32x4 p = *(const f32x4*)(part + d * 256 + r * 4);
            float s = p[0] + p[1] + p[2] + p[3] + bo[d];
            obuf[e] = 1.f / (1.f + __expf(-s));
        }
    }
    BAR();
    if (tid < 192) {
        f32x4 o = *(const f32x4*)((const float*)(smem + L_PS) + tid * 4);
        *(f32x4*)(out + (size_t)blockIdx.x * 768 + tid * 4) = o;
    }
}

// =====================================================================
extern "C" void kernel_launch(void* const* d_in, const int* in_sizes, int n_in,
                              void* d_out, int out_size, void* d_ws, size_t ws_size,
                              hipStream_t stream) {
    if (ws_size < (size_t)WS_NEED) return;

    const float* x      = (const float*)d_in[0];
    const float* W0     = (const float*)d_in[1];
    const float* b0     = (const float*)d_in[2];
    const float* g0     = (const float*)d_in[3];
    const float* bb0    = (const float*)d_in[4];
    const float* mm0    = (const float*)d_in[5];
    const float* vv0    = (const float*)d_in[6];
    const float* W1     = (const float*)d_in[7];
    const float* b1     = (const float*)d_in[8];
    const float* g1     = (const float*)d_in[9];
    const float* bb1    = (const float*)d_in[10];
    const float* mm1    = (const float*)d_in[11];
    const float* vv1    = (const float*)d_in[12];
    const float* w_init = (const float*)d_in[13];
    const float* b_init = (const float*)d_in[14];
    const float* Wz     = (const float*)d_in[15];
    const float* Wp     = (const float*)d_in[16];
    const float* bh     = (const float*)d_in[17];
    const float* Wo     = (const float*)d_in[18];
    const float* bo     = (const float*)d_in[19];
    const float* pred_w = (const float*)d_in[20];
    const int*   pred_idx = (const int*)d_in[21];

    char* ws = (char*)d_ws;
    const bf16_t* W0t = (const bf16_t*)(ws + WS_W0T);
    const bf16_t* W1t = (const bf16_t*)(ws + WS_W1T);
    const bf16_t* Wzt = (const bf16_t*)(ws + WS_WZT);
    const bf16_t* wiT = (const bf16_t*)(ws + WS_WIT);
    const float* al0 = (const float*)(ws + WS_AL0);
    const float* be0 = (const float*)(ws + WS_BE0);
    const float* al1 = (const float*)(ws + WS_AL1);
    const float* be1 = (const float*)(ws + WS_BE1);

    prep_kernel<<<dim3(512), dim3(256), 0, stream>>>(
        W0, b0, g0, bb0, mm0, vv0, W1, b1, g1, bb1, mm1, vv1, w_init, Wz, ws);

    fused_kernel<<<dim3(NBLK), dim3(256), 0, stream>>>(
        x, W0t, W1t, al0, be0, al1, be1, Wzt, wiT, b_init, Wp, bh, Wo, bo,
        pred_w, pred_idx, (float*)d_out);
}